// Round 5
// baseline (433.801 us; speedup 1.0000x reference)
//
#include <hip/hip_runtime.h>

typedef __attribute__((ext_vector_type(8))) short short8;
typedef __attribute__((ext_vector_type(4))) float f32x4;
typedef __attribute__((ext_vector_type(4))) unsigned short u16x4;

#define MFMA(a, b, c) __builtin_amdgcn_mfma_f32_16x16x32_bf16((a), (b), (c), 0, 0, 0)

namespace {
constexpr int IMG = 256;
constexpr int NWIN = 1024;
constexpr float SCALE = 0.17677669529663687f;  // 32^-0.5
}

__device__ __forceinline__ unsigned short f2bf(float f) {
    union { float f; unsigned u; } v; v.f = f;
    return (unsigned short)((v.u + 0x7FFFu + ((v.u >> 16) & 1u)) >> 16);
}
__device__ __forceinline__ float bf2f(unsigned short h) {
    union { unsigned u; float f; } v; v.u = ((unsigned)h) << 16;
    return v.f;
}
__device__ __forceinline__ unsigned pack2(float a, float b) {
    return (unsigned)f2bf(a) | ((unsigned)f2bf(b) << 16);
}

// fp32 [K][N] -> bf16 [N][K]
__global__ __launch_bounds__(256) void to_bf16_T(const float* __restrict__ in,
                                                 unsigned short* __restrict__ out,
                                                 int K, int N) {
    __shared__ float tile[32][65];
    const int t = threadIdx.x;
    const int nb = blockIdx.x * 64, kb = blockIdx.y * 32;
    const int tn = t & 63, tk = t >> 6;
#pragma unroll
    for (int p = 0; p < 8; ++p)
        tile[p * 4 + tk][tn] = in[(size_t)(kb + p * 4 + tk) * N + nb + tn];
    __syncthreads();
    const int n = t >> 2, kc = (t & 3) * 8;
    uint4 u;
    u.x = pack2(tile[kc + 0][n], tile[kc + 1][n]);
    u.y = pack2(tile[kc + 2][n], tile[kc + 3][n]);
    u.z = pack2(tile[kc + 4][n], tile[kc + 5][n]);
    u.w = pack2(tile[kc + 6][n], tile[kc + 7][n]);
    *(uint4*)(out + (size_t)(nb + n) * K + kb + kc) = u;
}

// bias2[((h*64+q)*16 + l15)*4 + nt] = rel_pos bias for (q, k=16*nt+l15), bf16
__global__ __launch_bounds__(256) void build_bias(const float* __restrict__ rel_pos,
                                                  unsigned short* __restrict__ bias2) {
    const int o = blockIdx.x * 256 + threadIdx.x;   // 0..24575
    const int nt = o & 3, l15 = (o >> 2) & 15, q = (o >> 6) & 63, h = o >> 12;
    const int k = 16 * nt + l15;
    const int qy = q >> 3, qx = q & 7, ky = k >> 3, kx = k & 7;
    bias2[o] = f2bf(rel_pos[h * 225 + (qy - ky + 7) * 15 + (qx - kx + 7)]);
}

__global__ __launch_bounds__(512, 4)
void wmsa_main(const float* __restrict__ x,
               const float* __restrict__ b_qkv,
               const unsigned short* __restrict__ bias2,
               const float* __restrict__ b_out,
               const unsigned short* __restrict__ wqT,   // bf16 [576][192]
               const unsigned short* __restrict__ woT,   // bf16 [192][192]
               float* __restrict__ out) {
    __shared__ unsigned short x_s[64][200];   // [tok][c]              25.6 KB
    __shared__ unsigned short qp_s[64][72];   // q(2 heads) / p(head0)  9.2 KB
    __shared__ unsigned short kp_s[64][72];   // k(2 heads) / p(head1)  9.2 KB
    __shared__ unsigned short vT_s[64][72];   // [d(2h*32)][tok]        9.2 KB
    __shared__ unsigned short oh_s[64][72];   // [tok][c(64)]           9.2 KB
    // total 62.4 KB -> 2 blocks/CU x 8 waves = 4 waves/SIMD

    const int tid = threadIdx.x;
    const int w   = tid >> 6;                 // wave 0..7
    const int l   = tid & 63;
    const int l15 = l & 15, lg = l >> 4;
    const int b   = blockIdx.x >> 10;
    const int win = blockIdx.x & (NWIN - 1);
    const int wy  = win >> 5, wx = win & 31;
    const bool lastwin = (win == NWIN - 1);
    const f32x4 z = {0.f, 0.f, 0.f, 0.f};

    // ---- stage x window -> bf16 LDS (roll(-4,-4) folded into pixel addr) ----
    for (int i = tid; i < 64 * 48; i += 512) {
        const int t = i / 48, c4 = i % 48;
        const int pr = ((wy << 3) + (t >> 3) + 4) & (IMG - 1);
        const int pc = ((wx << 3) + (t & 7) + 4) & (IMG - 1);
        const float4 xv = *reinterpret_cast<const float4*>(
            x + ((size_t)((b * IMG + pr) * IMG + pc)) * 192 + c4 * 4);
        uint2 pk; pk.x = pack2(xv.x, xv.y); pk.y = pack2(xv.z, xv.w);
        *(uint2*)(&x_s[t][c4 * 4]) = pk;
    }
    __syncthreads();

    // attention role: head within group + q-tile
    const int h_loc = w >> 2;          // 0..1
    const int qt    = w & 3;           // q-tile 0..3

    f32x4 g2[3][2];                    // GEMM2 accumulators: unit i, nt-half
#pragma unroll
    for (int i = 0; i < 3; ++i) { g2[i][0] = z; g2[i][1] = z; }

#pragma unroll 1
    for (int g = 0; g < 3; ++g) {      // head group: heads 2g, 2g+1
        // ==== phase 1: GEMM1 transposed D[col][tok]; 24 units (tile,nthalf), 3/wave ====
        f32x4 aq[3][2];
#pragma unroll
        for (int i = 0; i < 3; ++i) { aq[i][0] = z; aq[i][1] = z; }

#pragma unroll
        for (int ks = 0; ks < 6; ++ks) {
#pragma unroll
            for (int i = 0; i < 3; ++i) {
                const int u = 3 * w + i;
                const int t = u >> 1, nth = u & 1;
                const int which = t >> 2, sub = t & 3;
                const int hh = sub >> 1, d0 = (sub & 1) * 16;
                const int grow = which * 192 + (2 * g + hh) * 32 + d0 + l15;
                const short8 wf = *(const short8*)(wqT + (size_t)grow * 192 + ks * 32 + lg * 8);
#pragma unroll
                for (int nt2 = 0; nt2 < 2; ++nt2) {
                    const int nt = 2 * nth + nt2;
                    const short8 xf = *(const short8*)(&x_s[16 * nt + l15][ks * 32 + lg * 8]);
                    aq[i][nt2] = MFMA(wf, xf, aq[i][nt2]);
                }
            }
        }
        // epilogue: lane holds col=tok, rows = 4 consecutive qkv-cols d0+4lg+j
#pragma unroll
        for (int i = 0; i < 3; ++i) {
            const int u = 3 * w + i;
            const int t = u >> 1, nth = u & 1;
            const int which = t >> 2, sub = t & 3;
            const int hh = sub >> 1, d0 = (sub & 1) * 16;
            const int rbase = d0 + 4 * lg;
            const int bidx = which * 192 + (2 * g + hh) * 32 + rbase;
            const float b0 = b_qkv[bidx + 0], b1 = b_qkv[bidx + 1];
            const float b2 = b_qkv[bidx + 2], b3 = b_qkv[bidx + 3];
#pragma unroll
            for (int nt2 = 0; nt2 < 2; ++nt2) {
                const int nt = 2 * nth + nt2;
                const int tok = 16 * nt + l15;
                float v0 = aq[i][nt2][0] + b0, v1 = aq[i][nt2][1] + b1;
                float v2 = aq[i][nt2][2] + b2, v3 = aq[i][nt2][3] + b3;
                if (which == 0) {
                    v0 *= SCALE; v1 *= SCALE; v2 *= SCALE; v3 *= SCALE;
                    uint2 pk; pk.x = pack2(v0, v1); pk.y = pack2(v2, v3);
                    *(uint2*)(&qp_s[tok][hh * 32 + rbase]) = pk;
                } else if (which == 1) {
                    uint2 pk; pk.x = pack2(v0, v1); pk.y = pack2(v2, v3);
                    *(uint2*)(&kp_s[tok][hh * 32 + rbase]) = pk;
                } else {
                    const int dr = hh * 32 + rbase;
                    vT_s[dr + 0][tok] = f2bf(v0);
                    vT_s[dr + 1][tok] = f2bf(v1);
                    vT_s[dr + 2][tok] = f2bf(v2);
                    vT_s[dr + 3][tok] = f2bf(v3);
                }
            }
        }
        __syncthreads();   // A: q/k/vT ready

        // ==== phase 2a: S = q k^T for this wave's q-tile of its head ====
        const short8 qf = *(const short8*)(&qp_s[16 * qt + l15][h_loc * 32 + lg * 8]);
        f32x4 s[4];
#pragma unroll
        for (int nt = 0; nt < 4; ++nt) {
            const short8 kf = *(const short8*)(&kp_s[16 * nt + l15][h_loc * 32 + lg * 8]);
            s[nt] = MFMA(qf, kf, z);
        }
        __syncthreads();   // B: q/k buffers dead -> reuse as p

        // ==== phase 2b: softmax (no max-sub; |S+bias| bounded) ====
        unsigned short (*p_buf)[72] = (h_loc == 0) ? qp_s : kp_s;
        const int h = 2 * g + h_loc;
#pragma unroll
        for (int j = 0; j < 4; ++j) {
            const int q = 16 * qt + 4 * lg + j;
            const u16x4 bb = *(const u16x4*)(bias2 + (((h * 64 + q) * 16 + l15) << 2));
            float e[4], sum = 0.f;
#pragma unroll
            for (int nt = 0; nt < 4; ++nt) {
                float ee = __expf(s[nt][j] + bf2f(bb[nt]));
                if (lastwin && ((q < 4) != ((16 * nt + l15) < 4))) ee = 0.f;
                e[nt] = ee; sum += ee;
            }
            sum += __shfl_xor(sum, 1);
            sum += __shfl_xor(sum, 2);
            sum += __shfl_xor(sum, 4);
            sum += __shfl_xor(sum, 8);
            const float ri = __builtin_amdgcn_rcpf(sum);
#pragma unroll
            for (int nt = 0; nt < 4; ++nt)
                p_buf[q][16 * nt + l15] = f2bf(e[nt] * ri);
        }

        // ==== phase 3: O^T = V^T P^T (own p rows; vT stable since A) ====
        f32x4 o[2] = {z, z};
#pragma unroll
        for (int ks2 = 0; ks2 < 2; ++ks2) {
            const short8 pf = *(const short8*)(&p_buf[16 * qt + l15][ks2 * 32 + lg * 8]);
#pragma unroll
            for (int dm = 0; dm < 2; ++dm) {
                const short8 vf = *(const short8*)(&vT_s[h_loc * 32 + 16 * dm + l15][ks2 * 32 + lg * 8]);
                o[dm] = MFMA(vf, pf, o[dm]);
            }
        }
#pragma unroll
        for (int dm = 0; dm < 2; ++dm) {
            const int tok = 16 * qt + l15;
            const int c0 = h_loc * 32 + 16 * dm + 4 * lg;
            uint2 pk;
            pk.x = pack2(o[dm][0], o[dm][1]);
            pk.y = pack2(o[dm][2], o[dm][3]);
            *(uint2*)(&oh_s[tok][c0]) = pk;
        }
        __syncthreads();   // C: oh ready

        // ==== phase 4: GEMM2 partial, K-slice = this group's 64 channels ====
#pragma unroll
        for (int ks2 = 0; ks2 < 2; ++ks2) {
#pragma unroll
            for (int i = 0; i < 3; ++i) {
                const int u = 3 * w + i;
                const int oct = u >> 1, nth = u & 1;
                const short8 af = *(const short8*)(
                    woT + (size_t)(16 * oct + l15) * 192 + g * 64 + ks2 * 32 + lg * 8);
#pragma unroll
                for (int nt2 = 0; nt2 < 2; ++nt2) {
                    const int nt = 2 * nth + nt2;
                    const short8 bfr = *(const short8*)(&oh_s[16 * nt + l15][ks2 * 32 + lg * 8]);
                    g2[i][nt2] = MFMA(af, bfr, g2[i][nt2]);
                }
            }
        }
        // no barrier: next phase-1 writes (qp/kp/vT) sit behind next barrier A/B
        // relative to this group's oh reads; oh rewritten only after next A+B.
    }

    // ==== final store: D[oc][tok]; 6 float4 stores per lane ====
#pragma unroll
    for (int i = 0; i < 3; ++i) {
        const int u = 3 * w + i;
        const int oct = u >> 1, nth = u & 1;
        const int oc0 = 16 * oct + 4 * lg;
        const float4 bo = *reinterpret_cast<const float4*>(b_out + oc0);
#pragma unroll
        for (int nt2 = 0; nt2 < 2; ++nt2) {
            const int nt = 2 * nth + nt2;
            const int tok = 16 * nt + l15;
            const int pr = ((wy << 3) + (tok >> 3) + 4) & (IMG - 1);
            const int pc = ((wx << 3) + (tok & 7) + 4) & (IMG - 1);
            float* orow = out + (size_t)((b * IMG + pr) * IMG + pc) * 192;
            float4 vv;
            vv.x = g2[i][nt2][0] + bo.x; vv.y = g2[i][nt2][1] + bo.y;
            vv.z = g2[i][nt2][2] + bo.z; vv.w = g2[i][nt2][3] + bo.w;
            *reinterpret_cast<float4*>(orow + oc0) = vv;
        }
    }
}

extern "C" void kernel_launch(void* const* d_in, const int* in_sizes, int n_in,
                              void* d_out, int out_size, void* d_ws, size_t ws_size,
                              hipStream_t stream) {
    (void)in_sizes; (void)n_in; (void)out_size; (void)ws_size;
    const float* x       = (const float*)d_in[0];
    const float* w_qkv   = (const float*)d_in[1];
    const float* b_qkv   = (const float*)d_in[2];
    const float* rel_pos = (const float*)d_in[3];
    const float* w_out   = (const float*)d_in[4];
    const float* b_out   = (const float*)d_in[5];
    float* out = (float*)d_out;

    unsigned short* wqT   = (unsigned short*)d_ws;       // 576*192 bf16
    unsigned short* woT   = wqT + 576 * 192;             // 192*192 bf16
    unsigned short* bias2 = woT + 192 * 192;             // 24576 bf16 (total 344064 B)

    to_bf16_T<<<dim3(9, 6), 256, 0, stream>>>(w_qkv, wqT, 192, 576);
    to_bf16_T<<<dim3(3, 6), 256, 0, stream>>>(w_out, woT, 192, 192);
    build_bias<<<dim3(96), 256, 0, stream>>>(rel_pos, bias2);

    wmsa_main<<<dim3(4 * NWIN), dim3(512), 0, stream>>>(
        x, b_qkv, bias2, b_out, wqT, woT, out);
}

// Round 6
// 397.390 us; speedup vs baseline: 1.0916x; 1.0916x over previous
//
#include <hip/hip_runtime.h>

typedef __attribute__((ext_vector_type(8))) short short8;
typedef __attribute__((ext_vector_type(4))) float f32x4;
typedef __attribute__((ext_vector_type(4))) unsigned short u16x4;

#define MFMA(a, b, c) __builtin_amdgcn_mfma_f32_16x16x32_bf16((a), (b), (c), 0, 0, 0)

namespace {
constexpr int IMG = 256;
constexpr int NWIN = 1024;
constexpr float SCALE = 0.17677669529663687f;  // 32^-0.5
}

__device__ __forceinline__ unsigned short f2bf(float f) {
    union { float f; unsigned u; } v; v.f = f;
    return (unsigned short)((v.u + 0x7FFFu + ((v.u >> 16) & 1u)) >> 16);
}
__device__ __forceinline__ float bf2f(unsigned short h) {
    union { unsigned u; float f; } v; v.u = ((unsigned)h) << 16;
    return v.f;
}
__device__ __forceinline__ unsigned pack2(float a, float b) {
    return (unsigned)f2bf(a) | ((unsigned)f2bf(b) << 16);
}

// fp32 [K][N] -> bf16 [N][K]
__global__ __launch_bounds__(256) void to_bf16_T(const float* __restrict__ in,
                                                 unsigned short* __restrict__ out,
                                                 int K, int N) {
    __shared__ float tile[32][65];
    const int t = threadIdx.x;
    const int nb = blockIdx.x * 64, kb = blockIdx.y * 32;
    const int tn = t & 63, tk = t >> 6;
#pragma unroll
    for (int p = 0; p < 8; ++p)
        tile[p * 4 + tk][tn] = in[(size_t)(kb + p * 4 + tk) * N + nb + tn];
    __syncthreads();
    const int n = t >> 2, kc = (t & 3) * 8;
    uint4 u;
    u.x = pack2(tile[kc + 0][n], tile[kc + 1][n]);
    u.y = pack2(tile[kc + 2][n], tile[kc + 3][n]);
    u.z = pack2(tile[kc + 4][n], tile[kc + 5][n]);
    u.w = pack2(tile[kc + 6][n], tile[kc + 7][n]);
    *(uint4*)(out + (size_t)(nb + n) * K + kb + kc) = u;
}

// bias2[((h*64+q)*16 + l15)*4 + nt] = rel_pos bias for (q, k=16*nt+l15), bf16
__global__ __launch_bounds__(256) void build_bias(const float* __restrict__ rel_pos,
                                                  unsigned short* __restrict__ bias2) {
    const int o = blockIdx.x * 256 + threadIdx.x;   // 0..24575
    const int nt = o & 3, l15 = (o >> 2) & 15, q = (o >> 6) & 63, h = o >> 12;
    const int k = 16 * nt + l15;
    const int qy = q >> 3, qx = q & 7, ky = k >> 3, kx = k & 7;
    bias2[o] = f2bf(rel_pos[h * 225 + (qy - ky + 7) * 15 + (qx - kx + 7)]);
}

// ============================ K1: QKV projection ============================
// Per-window GEMM1 (transposed D[col][tok]); q,k straight to global; v via LDS
// transpose to vT_ws[win][h][d][tok].
__global__ __launch_bounds__(256, 4)
void qkv_proj(const float* __restrict__ x,
              const float* __restrict__ b_qkv,
              const unsigned short* __restrict__ wqT,     // bf16 [576][192]
              unsigned short* __restrict__ q_ws,          // [4096][6][64][32]
              unsigned short* __restrict__ k_ws,          // [4096][6][64][32]
              unsigned short* __restrict__ vT_ws) {       // [4096][6][32][64]
    __shared__ unsigned short x_s[64][200];   // 25.6 KB
    __shared__ unsigned short vT_s[64][72];   //  9.2 KB  -> 34.8 KB, 4 blocks/CU

    const int tid = threadIdx.x;
    const int w   = tid >> 6;
    const int l   = tid & 63;
    const int l15 = l & 15, lg = l >> 4;
    const int wing = blockIdx.x;              // global window id
    const int b   = wing >> 10;
    const int win = wing & (NWIN - 1);
    const int wy  = win >> 5, wx = win & 31;
    const f32x4 z = {0.f, 0.f, 0.f, 0.f};

    // stage x window -> bf16 LDS (roll(-4,-4) folded into pixel address)
    for (int i = tid; i < 64 * 48; i += 256) {
        const int t = i / 48, c4 = i % 48;
        const int pr = ((wy << 3) + (t >> 3) + 4) & (IMG - 1);
        const int pc = ((wx << 3) + (t & 7) + 4) & (IMG - 1);
        const float4 xv = *reinterpret_cast<const float4*>(
            x + ((size_t)((b * IMG + pr) * IMG + pc)) * 192 + c4 * 4);
        uint2 pk; pk.x = pack2(xv.x, xv.y); pk.y = pack2(xv.z, xv.w);
        *(uint2*)(&x_s[t][c4 * 4]) = pk;
    }
    __syncthreads();

#pragma unroll 1
    for (int g = 0; g < 3; ++g) {             // heads 2g, 2g+1
        f32x4 aq[3][4];
#pragma unroll
        for (int ci = 0; ci < 3; ++ci)
#pragma unroll
            for (int nt = 0; nt < 4; ++nt) aq[ci][nt] = z;

#pragma unroll
        for (int ks = 0; ks < 6; ++ks) {
            short8 xf[4];
#pragma unroll
            for (int nt = 0; nt < 4; ++nt)
                xf[nt] = *(const short8*)(&x_s[16 * nt + l15][ks * 32 + lg * 8]);
#pragma unroll
            for (int ci = 0; ci < 3; ++ci) {
                const int t = w + 4 * ci;                 // col-tile 0..11
                const int which = t >> 2, sub = t & 3;
                const int hh = sub >> 1, d0 = (sub & 1) * 16;
                const int grow = which * 192 + (2 * g + hh) * 32 + d0 + l15;
                const short8 wf = *(const short8*)(wqT + (size_t)grow * 192 + ks * 32 + lg * 8);
#pragma unroll
                for (int nt = 0; nt < 4; ++nt) aq[ci][nt] = MFMA(wf, xf[nt], aq[ci][nt]);
            }
        }
        // epilogue
#pragma unroll
        for (int ci = 0; ci < 3; ++ci) {
            const int t = w + 4 * ci;
            const int which = t >> 2, sub = t & 3;
            const int hh = sub >> 1, d0 = (sub & 1) * 16;
            const int rbase = d0 + 4 * lg;
            const int h = 2 * g + hh;
            const int bidx = which * 192 + h * 32 + rbase;
            const float b0 = b_qkv[bidx + 0], b1 = b_qkv[bidx + 1];
            const float b2 = b_qkv[bidx + 2], b3 = b_qkv[bidx + 3];
#pragma unroll
            for (int nt = 0; nt < 4; ++nt) {
                const int tok = 16 * nt + l15;
                float v0 = aq[ci][nt][0] + b0, v1 = aq[ci][nt][1] + b1;
                float v2 = aq[ci][nt][2] + b2, v3 = aq[ci][nt][3] + b3;
                if (which == 0) {
                    v0 *= SCALE; v1 *= SCALE; v2 *= SCALE; v3 *= SCALE;
                    uint2 pk; pk.x = pack2(v0, v1); pk.y = pack2(v2, v3);
                    *(uint2*)(q_ws + ((size_t)(wing * 6 + h) * 64 + tok) * 32 + rbase) = pk;
                } else if (which == 1) {
                    uint2 pk; pk.x = pack2(v0, v1); pk.y = pack2(v2, v3);
                    *(uint2*)(k_ws + ((size_t)(wing * 6 + h) * 64 + tok) * 32 + rbase) = pk;
                } else {
                    const int dr = hh * 32 + rbase;
                    vT_s[dr + 0][tok] = f2bf(v0);
                    vT_s[dr + 1][tok] = f2bf(v1);
                    vT_s[dr + 2][tok] = f2bf(v2);
                    vT_s[dr + 3][tok] = f2bf(v3);
                }
            }
        }
        __syncthreads();   // vT_s scatter complete
        // coalesced vT store: 64 rows x 128 B
        for (int i = tid; i < 512; i += 256) {
            const int r = i >> 3, seg = i & 7;
            const uint4 u = *(const uint4*)(&vT_s[r][seg * 8]);
            const int h = 2 * g + (r >> 5), d = r & 31;
            *(uint4*)(vT_ws + ((size_t)(wing * 6 + h) * 32 + d) * 64 + seg * 8) = u;
        }
        if (g < 2) __syncthreads();   // protect vT_s reads vs next group's scatter
    }
}

// ======================= K2: attention + out projection =====================
// 512 thr / 8 waves; wave-private p (no barriers in attention); 1 barrier.
__global__ __launch_bounds__(512, 4)
void attn_out(const unsigned short* __restrict__ bias2,
              const float* __restrict__ b_out,
              const unsigned short* __restrict__ woT,     // bf16 [192][192]
              const unsigned short* __restrict__ q_ws,
              const unsigned short* __restrict__ k_ws,
              const unsigned short* __restrict__ vT_ws,
              float* __restrict__ out) {
    __shared__ unsigned short oh_s[64][200];   // [tok][c] 25.6 KB
    __shared__ unsigned short p_s[8][16][72];  // wave-private P, 18.4 KB -> 44 KB

    const int tid = threadIdx.x;
    const int w   = tid >> 6;                  // 0..7
    const int l   = tid & 63;
    const int l15 = l & 15, lg = l >> 4;
    const int wing = blockIdx.x;
    const int b   = wing >> 10;
    const int win = wing & (NWIN - 1);
    const int wy  = win >> 5, wx = win & 31;
    const bool lastwin = (win == NWIN - 1);
    const f32x4 z = {0.f, 0.f, 0.f, 0.f};

    // ---- attention: 24 (h,qt) units, 3 per wave, fully barrier-free ----
#pragma unroll 1
    for (int i = 0; i < 3; ++i) {
        const int u = 3 * w + i;
        const int h = u >> 2, qt = u & 3;
        const size_t qkbase = ((size_t)(wing * 6 + h) * 64) * 32;

        const short8 qf = *(const short8*)(q_ws + qkbase + (16 * qt + l15) * 32 + lg * 8);
        f32x4 s[4];
#pragma unroll
        for (int nt = 0; nt < 4; ++nt) {
            const short8 kf = *(const short8*)(k_ws + qkbase + (16 * nt + l15) * 32 + lg * 8);
            s[nt] = MFMA(qf, kf, z);
        }
        // softmax (no max-sub; |S+bias| bounded)
#pragma unroll
        for (int j = 0; j < 4; ++j) {
            const int q = 16 * qt + 4 * lg + j;
            const u16x4 bb = *(const u16x4*)(bias2 + (((h * 64 + q) * 16 + l15) << 2));
            float e[4], sum = 0.f;
#pragma unroll
            for (int nt = 0; nt < 4; ++nt) {
                float ee = __expf(s[nt][j] + bf2f(bb[nt]));
                if (lastwin && ((q < 4) != ((16 * nt + l15) < 4))) ee = 0.f;
                e[nt] = ee; sum += ee;
            }
            sum += __shfl_xor(sum, 1);
            sum += __shfl_xor(sum, 2);
            sum += __shfl_xor(sum, 4);
            sum += __shfl_xor(sum, 8);
            const float ri = __builtin_amdgcn_rcpf(sum);
#pragma unroll
            for (int nt = 0; nt < 4; ++nt)
                p_s[w][4 * lg + j][16 * nt + l15] = f2bf(e[nt] * ri);
        }
        // PV: O^T = V^T P^T (p private to this wave; intra-wave LDS order ok)
        f32x4 o[2] = {z, z};
#pragma unroll
        for (int ks2 = 0; ks2 < 2; ++ks2) {
            const short8 pf = *(const short8*)(&p_s[w][l15][ks2 * 32 + lg * 8]);
#pragma unroll
            for (int dm = 0; dm < 2; ++dm) {
                const short8 vf = *(const short8*)(
                    vT_ws + ((size_t)(wing * 6 + h) * 32 + 16 * dm + l15) * 64 + ks2 * 32 + lg * 8);
                o[dm] = MFMA(vf, pf, o[dm]);
            }
        }
#pragma unroll
        for (int dm = 0; dm < 2; ++dm) {
            const int tok = 16 * qt + l15;
            const int c0 = h * 32 + 16 * dm + 4 * lg;
            uint2 pk;
            pk.x = pack2(o[dm][0], o[dm][1]);
            pk.y = pack2(o[dm][2], o[dm][3]);
            *(uint2*)(&oh_s[tok][c0]) = pk;
        }
    }
    __syncthreads();   // the only barrier: oh complete

    // ---- GEMM2 transposed: out^T[oc][tok]; 24 units (oct,nth), 3 per wave ----
    f32x4 g2[3][2];
#pragma unroll
    for (int i = 0; i < 3; ++i) { g2[i][0] = z; g2[i][1] = z; }
#pragma unroll
    for (int ks = 0; ks < 6; ++ks) {
#pragma unroll
        for (int i = 0; i < 3; ++i) {
            const int u = 3 * w + i;
            const int oct = u >> 1, nth = u & 1;
            const short8 af = *(const short8*)(
                woT + (size_t)(16 * oct + l15) * 192 + ks * 32 + lg * 8);
#pragma unroll
            for (int nt2 = 0; nt2 < 2; ++nt2) {
                const int nt = 2 * nth + nt2;
                const short8 bfr = *(const short8*)(&oh_s[16 * nt + l15][ks * 32 + lg * 8]);
                g2[i][nt2] = MFMA(af, bfr, g2[i][nt2]);
            }
        }
    }
#pragma unroll
    for (int i = 0; i < 3; ++i) {
        const int u = 3 * w + i;
        const int oct = u >> 1, nth = u & 1;
        const int oc0 = 16 * oct + 4 * lg;
        const float4 bo = *reinterpret_cast<const float4*>(b_out + oc0);
#pragma unroll
        for (int nt2 = 0; nt2 < 2; ++nt2) {
            const int nt = 2 * nth + nt2;
            const int tok = 16 * nt + l15;
            const int pr = ((wy << 3) + (tok >> 3) + 4) & (IMG - 1);
            const int pc = ((wx << 3) + (tok & 7) + 4) & (IMG - 1);
            float* orow = out + (size_t)((b * IMG + pr) * IMG + pc) * 192;
            float4 vv;
            vv.x = g2[i][nt2][0] + bo.x; vv.y = g2[i][nt2][1] + bo.y;
            vv.z = g2[i][nt2][2] + bo.z; vv.w = g2[i][nt2][3] + bo.w;
            *reinterpret_cast<float4*>(orow + oc0) = vv;
        }
    }
}

// ===================== fallback: R4 fused kernel (proven 319 us) ============
__global__ __launch_bounds__(256, 2)
void wmsa_fused(const float* __restrict__ x,
                const float* __restrict__ b_qkv,
                const unsigned short* __restrict__ bias2,
                const float* __restrict__ b_out,
                const unsigned short* __restrict__ wqT,
                const unsigned short* __restrict__ woT,
                float* __restrict__ out) {
    __shared__ unsigned short x_s[64][200];
    __shared__ unsigned short qp_s[64][72];
    __shared__ unsigned short kp_s[64][72];
    __shared__ unsigned short vT_s[64][72];
    __shared__ unsigned short oh_s[64][72];

    const int tid = threadIdx.x;
    const int w   = tid >> 6;
    const int l   = tid & 63;
    const int l15 = l & 15, lg = l >> 4;
    const int b   = blockIdx.x >> 10;
    const int win = blockIdx.x & (NWIN - 1);
    const int wy  = win >> 5, wx = win & 31;
    const bool lastwin = (win == NWIN - 1);
    const f32x4 z = {0.f, 0.f, 0.f, 0.f};

    for (int i = tid; i < 64 * 48; i += 256) {
        const int t = i / 48, c4 = i % 48;
        const int pr = ((wy << 3) + (t >> 3) + 4) & (IMG - 1);
        const int pc = ((wx << 3) + (t & 7) + 4) & (IMG - 1);
        const float4 xv = *reinterpret_cast<const float4*>(
            x + ((size_t)((b * IMG + pr) * IMG + pc)) * 192 + c4 * 4);
        uint2 pk; pk.x = pack2(xv.x, xv.y); pk.y = pack2(xv.z, xv.w);
        *(uint2*)(&x_s[t][c4 * 4]) = pk;
    }
    __syncthreads();

    const int h_loc = w >> 1;
    const int qt0   = 2 * (w & 1);

    f32x4 g2[3][4];
#pragma unroll
    for (int mi = 0; mi < 3; ++mi)
#pragma unroll
        for (int nt = 0; nt < 4; ++nt) g2[mi][nt] = z;

#pragma unroll 1
    for (int g = 0; g < 3; ++g) {
        f32x4 aq[3][4];
#pragma unroll
        for (int ci = 0; ci < 3; ++ci)
#pragma unroll
            for (int nt = 0; nt < 4; ++nt) aq[ci][nt] = z;

#pragma unroll
        for (int ks = 0; ks < 6; ++ks) {
            short8 xf[4];
#pragma unroll
            for (int nt = 0; nt < 4; ++nt)
                xf[nt] = *(const short8*)(&x_s[16 * nt + l15][ks * 32 + lg * 8]);
#pragma unroll
            for (int ci = 0; ci < 3; ++ci) {
                const int t = w + 4 * ci;
                const int which = t >> 2, sub = t & 3;
                const int hh = sub >> 1, d0 = (sub & 1) * 16;
                const int grow = which * 192 + (2 * g + hh) * 32 + d0 + l15;
                const short8 wf = *(const short8*)(wqT + (size_t)grow * 192 + ks * 32 + lg * 8);
#pragma unroll
                for (int nt = 0; nt < 4; ++nt) aq[ci][nt] = MFMA(wf, xf[nt], aq[ci][nt]);
            }
        }
#pragma unroll
        for (int ci = 0; ci < 3; ++ci) {
            const int t = w + 4 * ci;
            const int which = t >> 2, sub = t & 3;
            const int hh = sub >> 1, d0 = (sub & 1) * 16;
            const int rbase = d0 + 4 * lg;
            const int bidx = which * 192 + (2 * g + hh) * 32 + rbase;
            const float b0 = b_qkv[bidx + 0], b1 = b_qkv[bidx + 1];
            const float b2 = b_qkv[bidx + 2], b3 = b_qkv[bidx + 3];
#pragma unroll
            for (int nt = 0; nt < 4; ++nt) {
                const int tok = 16 * nt + l15;
                float v0 = aq[ci][nt][0] + b0, v1 = aq[ci][nt][1] + b1;
                float v2 = aq[ci][nt][2] + b2, v3 = aq[ci][nt][3] + b3;
                if (which == 0) {
                    v0 *= SCALE; v1 *= SCALE; v2 *= SCALE; v3 *= SCALE;
                    uint2 pk; pk.x = pack2(v0, v1); pk.y = pack2(v2, v3);
                    *(uint2*)(&qp_s[tok][hh * 32 + rbase]) = pk;
                } else if (which == 1) {
                    uint2 pk; pk.x = pack2(v0, v1); pk.y = pack2(v2, v3);
                    *(uint2*)(&kp_s[tok][hh * 32 + rbase]) = pk;
                } else {
                    const int dr = hh * 32 + rbase;
                    vT_s[dr + 0][tok] = f2bf(v0);
                    vT_s[dr + 1][tok] = f2bf(v1);
                    vT_s[dr + 2][tok] = f2bf(v2);
                    vT_s[dr + 3][tok] = f2bf(v3);
                }
            }
        }
        __syncthreads();

        short8 qf[2], kf[4];
#pragma unroll
        for (int mq = 0; mq < 2; ++mq)
            qf[mq] = *(const short8*)(&qp_s[16 * (qt0 + mq) + l15][h_loc * 32 + lg * 8]);
#pragma unroll
        for (int nt = 0; nt < 4; ++nt)
            kf[nt] = *(const short8*)(&kp_s[16 * nt + l15][h_loc * 32 + lg * 8]);
        f32x4 s[2][4];
#pragma unroll
        for (int mq = 0; mq < 2; ++mq)
#pragma unroll
            for (int nt = 0; nt < 4; ++nt) s[mq][nt] = MFMA(qf[mq], kf[nt], z);
        __syncthreads();

        unsigned short (*p_buf)[72] = (h_loc == 0) ? qp_s : kp_s;
        const int h = 2 * g + h_loc;
#pragma unroll
        for (int mq = 0; mq < 2; ++mq) {
#pragma unroll
            for (int j = 0; j < 4; ++j) {
                const int q = 16 * (qt0 + mq) + 4 * lg + j;
                const u16x4 bb = *(const u16x4*)(bias2 + (((h * 64 + q) * 16 + l15) << 2));
                float e[4], sum = 0.f;
#pragma unroll
                for (int nt = 0; nt < 4; ++nt) {
                    float ee = __expf(s[mq][nt][j] + bf2f(bb[nt]));
                    if (lastwin && ((q < 4) != ((16 * nt + l15) < 4))) ee = 0.f;
                    e[nt] = ee; sum += ee;
                }
                sum += __shfl_xor(sum, 1);
                sum += __shfl_xor(sum, 2);
                sum += __shfl_xor(sum, 4);
                sum += __shfl_xor(sum, 8);
                const float ri = __builtin_amdgcn_rcpf(sum);
#pragma unroll
                for (int nt = 0; nt < 4; ++nt)
                    p_buf[q][16 * nt + l15] = f2bf(e[nt] * ri);
            }
        }

        f32x4 o[2][2];
#pragma unroll
        for (int dm = 0; dm < 2; ++dm)
#pragma unroll
            for (int qn = 0; qn < 2; ++qn) o[dm][qn] = z;
#pragma unroll
        for (int ks2 = 0; ks2 < 2; ++ks2) {
            short8 pf[2];
#pragma unroll
            for (int qn = 0; qn < 2; ++qn)
                pf[qn] = *(const short8*)(&p_buf[16 * (qt0 + qn) + l15][ks2 * 32 + lg * 8]);
#pragma unroll
            for (int dm = 0; dm < 2; ++dm) {
                const short8 vf = *(const short8*)(&vT_s[h_loc * 32 + 16 * dm + l15][ks2 * 32 + lg * 8]);
#pragma unroll
                for (int qn = 0; qn < 2; ++qn) o[dm][qn] = MFMA(vf, pf[qn], o[dm][qn]);
            }
        }
#pragma unroll
        for (int dm = 0; dm < 2; ++dm)
#pragma unroll
            for (int qn = 0; qn < 2; ++qn) {
                const int tok = 16 * (qt0 + qn) + l15;
                const int c0 = h_loc * 32 + 16 * dm + 4 * lg;
                uint2 pk;
                pk.x = pack2(o[dm][qn][0], o[dm][qn][1]);
                pk.y = pack2(o[dm][qn][2], o[dm][qn][3]);
                *(uint2*)(&oh_s[tok][c0]) = pk;
            }
        __syncthreads();

#pragma unroll
        for (int ks2 = 0; ks2 < 2; ++ks2) {
            short8 bfr[4];
#pragma unroll
            for (int nt = 0; nt < 4; ++nt)
                bfr[nt] = *(const short8*)(&oh_s[16 * nt + l15][ks2 * 32 + lg * 8]);
#pragma unroll
            for (int mi = 0; mi < 3; ++mi) {
                const int oct = w + 4 * mi;
                const short8 af = *(const short8*)(
                    woT + (size_t)(16 * oct + l15) * 192 + g * 64 + ks2 * 32 + lg * 8);
#pragma unroll
                for (int nt = 0; nt < 4; ++nt) g2[mi][nt] = MFMA(af, bfr[nt], g2[mi][nt]);
            }
        }
    }

#pragma unroll
    for (int nt = 0; nt < 4; ++nt) {
        const int tok = 16 * nt + l15;
        const int pr = ((wy << 3) + (tok >> 3) + 4) & (IMG - 1);
        const int pc = ((wx << 3) + (tok & 7) + 4) & (IMG - 1);
        float* orow = out + (size_t)((b * IMG + pr) * IMG + pc) * 192;
#pragma unroll
        for (int mi = 0; mi < 3; ++mi) {
            const int oc0 = 16 * (w + 4 * mi) + 4 * lg;
            const float4 bo = *reinterpret_cast<const float4*>(b_out + oc0);
            float4 vv;
            vv.x = g2[mi][nt][0] + bo.x; vv.y = g2[mi][nt][1] + bo.y;
            vv.z = g2[mi][nt][2] + bo.z; vv.w = g2[mi][nt][3] + bo.w;
            *reinterpret_cast<float4*>(orow + oc0) = vv;
        }
    }
}

extern "C" void kernel_launch(void* const* d_in, const int* in_sizes, int n_in,
                              void* d_out, int out_size, void* d_ws, size_t ws_size,
                              hipStream_t stream) {
    (void)in_sizes; (void)n_in; (void)out_size;
    const float* x       = (const float*)d_in[0];
    const float* w_qkv   = (const float*)d_in[1];
    const float* b_qkv   = (const float*)d_in[2];
    const float* rel_pos = (const float*)d_in[3];
    const float* w_out   = (const float*)d_in[4];
    const float* b_out   = (const float*)d_in[5];
    float* out = (float*)d_out;

    unsigned short* wqT   = (unsigned short*)d_ws;       // 110592 hw
    unsigned short* woT   = wqT + 576 * 192;             //  36864 hw
    unsigned short* bias2 = woT + 192 * 192;             //  24576 hw
    unsigned short* q_ws  = bias2 + 24576;               // 50331648 hw each
    unsigned short* k_ws  = q_ws + (size_t)4096 * 6 * 64 * 32;
    unsigned short* vT_ws = k_ws + (size_t)4096 * 6 * 64 * 32;

    const size_t need = (size_t)344064 + 3u * (size_t)4096 * 6 * 64 * 32 * 2;

    to_bf16_T<<<dim3(9, 6), 256, 0, stream>>>(w_qkv, wqT, 192, 576);
    to_bf16_T<<<dim3(3, 6), 256, 0, stream>>>(w_out, woT, 192, 192);
    build_bias<<<dim3(96), 256, 0, stream>>>(rel_pos, bias2);

    if (ws_size >= need) {
        qkv_proj<<<dim3(4 * NWIN), dim3(256), 0, stream>>>(
            x, b_qkv, wqT, q_ws, k_ws, vT_ws);
        attn_out<<<dim3(4 * NWIN), dim3(512), 0, stream>>>(
            bias2, b_out, woT, q_ws, k_ws, vT_ws, out);
    } else {
        wmsa_fused<<<dim3(4 * NWIN), dim3(256), 0, stream>>>(
            x, b_qkv, bias2, b_out, wqT, woT, out);
    }
}

// Round 8
// 325.869 us; speedup vs baseline: 1.3312x; 1.2195x over previous
//
#include <hip/hip_runtime.h>
#include <hip/hip_bf16.h>

typedef __attribute__((ext_vector_type(8))) short short8;
typedef __attribute__((ext_vector_type(4))) float f32x4;
typedef __attribute__((ext_vector_type(4))) unsigned short u16x4;

#define MFMA(a, b, c) __builtin_amdgcn_mfma_f32_16x16x32_bf16((a), (b), (c), 0, 0, 0)

namespace {
constexpr int IMG = 256;
constexpr int NWIN = 1024;
constexpr float SCALE = 0.17677669529663687f;  // 32^-0.5
constexpr float L2E   = 1.4426950408889634f;   // log2(e)
}

__device__ __forceinline__ unsigned short f2bf1(float f) {
    __hip_bfloat16 h = __float2bfloat16(f);
    union { __hip_bfloat16 h; unsigned short u; } v; v.h = h;
    return v.u;
}
__device__ __forceinline__ unsigned pack2(float a, float b) {
    __hip_bfloat162 h = __float22bfloat162_rn(make_float2(a, b));
    union { __hip_bfloat162 h; unsigned u; } v; v.h = h;
    return v.u;
}
__device__ __forceinline__ float bf2f(unsigned short h) {
    union { unsigned u; float f; } v; v.u = ((unsigned)h) << 16;
    return v.f;
}

// fp32 [K][N] -> bf16 [N][K]; output rows (= original cols) < scale_n get *scale
__global__ __launch_bounds__(256) void to_bf16_T(const float* __restrict__ in,
                                                 unsigned short* __restrict__ out,
                                                 int K, int N, int scale_n, float scale) {
    __shared__ float tile[32][65];
    const int t = threadIdx.x;
    const int nb = blockIdx.x * 64, kb = blockIdx.y * 32;
    const int tn = t & 63, tk = t >> 6;
#pragma unroll
    for (int p = 0; p < 8; ++p)
        tile[p * 4 + tk][tn] = in[(size_t)(kb + p * 4 + tk) * N + nb + tn];
    __syncthreads();
    const int n = t >> 2, kc = (t & 3) * 8;
    const float s = (nb + n) < scale_n ? scale : 1.0f;
    uint4 u;
    u.x = pack2(tile[kc + 0][n] * s, tile[kc + 1][n] * s);
    u.y = pack2(tile[kc + 2][n] * s, tile[kc + 3][n] * s);
    u.z = pack2(tile[kc + 4][n] * s, tile[kc + 5][n] * s);
    u.w = pack2(tile[kc + 6][n] * s, tile[kc + 7][n] * s);
    *(uint4*)(out + (size_t)(nb + n) * K + kb + kc) = u;
}

// bias tables (pre-multiplied by log2e): bias2[o], bias2m[o] (masked -> -3e4)
// o = ((h*64+q)*16 + l15)*4 + nt, k = 16*nt + l15. Also bq2[576] (q-part * SCALE).
__global__ __launch_bounds__(256) void build_bias(const float* __restrict__ rel_pos,
                                                  const float* __restrict__ b_qkv,
                                                  unsigned short* __restrict__ bias2,
                                                  float* __restrict__ bq2) {
    const int o = blockIdx.x * 256 + threadIdx.x;   // 0..24575
    const int nt = o & 3, l15 = (o >> 2) & 15, q = (o >> 6) & 63, h = o >> 12;
    const int k = 16 * nt + l15;
    const int qy = q >> 3, qx = q & 7, ky = k >> 3, kx = k & 7;
    const float bv = rel_pos[h * 225 + (qy - ky + 7) * 15 + (qx - kx + 7)] * L2E;
    bias2[o] = f2bf1(bv);
    const bool masked = (q < 4) != (k < 4);
    bias2[24576 + o] = masked ? f2bf1(-30000.0f) : f2bf1(bv);
    if (blockIdx.x == 0) {
        for (int i = threadIdx.x; i < 576; i += 256)      // FIX: cover all 576
            bq2[i] = b_qkv[i] * (i < 192 ? SCALE : 1.0f);
    }
}

// ================= K1: GEMM1 (bias C-init) + attention -> oh_ws (bf16) =======
__global__ __launch_bounds__(256, 3)
void qkv_attn(const float* __restrict__ x,
              const float* __restrict__ bq2,
              const unsigned short* __restrict__ bias2,  // [2][24576], *log2e
              const unsigned short* __restrict__ wqT,    // bf16 [576][192], q-rows pre-scaled
              unsigned short* __restrict__ oh_ws) {      // [4096][64][192]
    __shared__ unsigned short x_s[64][200];   // 25.6 KB
    __shared__ unsigned short qp_s[64][72];   //  9.2 KB  (q / p-head0)
    __shared__ unsigned short kp_s[64][72];   //  9.2 KB  (k / p-head1)
    __shared__ unsigned short vT_s[64][72];   //  9.2 KB  -> 53248 B, 3 blocks/CU

    const int tid = threadIdx.x;
    const int w   = tid >> 6;
    const int l   = tid & 63;
    const int l15 = l & 15, lg = l >> 4;
    const int wing = blockIdx.x;
    const int b   = wing >> 10;
    const int win = wing & (NWIN - 1);
    const int wy  = win >> 5, wx = win & 31;
    const unsigned short* bias_t = bias2 + ((win == NWIN - 1) ? 24576 : 0);

    // stage x window -> bf16 LDS (roll(-4,-4) folded into pixel address)
    for (int i = tid; i < 64 * 48; i += 256) {
        const int t = i / 48, c4 = i % 48;
        const int pr = ((wy << 3) + (t >> 3) + 4) & (IMG - 1);
        const int pc = ((wx << 3) + (t & 7) + 4) & (IMG - 1);
        const float4 xv = *reinterpret_cast<const float4*>(
            x + ((size_t)((b * IMG + pr) * IMG + pc)) * 192 + c4 * 4);
        uint2 pk; pk.x = pack2(xv.x, xv.y); pk.y = pack2(xv.z, xv.w);
        *(uint2*)(&x_s[t][c4 * 4]) = pk;
    }
    __syncthreads();

    const int h_loc = w >> 1;
    const int qt0   = 2 * (w & 1);

#pragma unroll 1
    for (int g = 0; g < 3; ++g) {             // heads 2g, 2g+1
        // ==== phase 1: GEMM1; wave owns col-tiles {w, w+4, w+8}; bias via C-init
        f32x4 aq[3][4];
#pragma unroll
        for (int ci = 0; ci < 3; ++ci) {
            const int t = w + 4 * ci;
            const int which = t >> 2, sub = t & 3;
            const int hh = sub >> 1, d0 = (sub & 1) * 16;
            f32x4 c0;
            if (which < 2) {                   // transposed D[col][tok]: bias per row
                const float4 b4 = *reinterpret_cast<const float4*>(
                    bq2 + which * 192 + (2 * g + hh) * 32 + d0 + 4 * lg);
                c0 = f32x4{b4.x, b4.y, b4.z, b4.w};
            } else {                           // normal D[tok][vcol]: bias per col
                const float bb = bq2[384 + (2 * g + hh) * 32 + d0 + l15];
                c0 = f32x4{bb, bb, bb, bb};
            }
#pragma unroll
            for (int nt = 0; nt < 4; ++nt) aq[ci][nt] = c0;
        }

#pragma unroll
        for (int ks = 0; ks < 6; ++ks) {
            short8 xf[4];
#pragma unroll
            for (int nt = 0; nt < 4; ++nt)
                xf[nt] = *(const short8*)(&x_s[16 * nt + l15][ks * 32 + lg * 8]);
#pragma unroll
            for (int ci = 0; ci < 3; ++ci) {
                const int t = w + 4 * ci;
                const int which = t >> 2, sub = t & 3;
                const int hh = sub >> 1, d0 = (sub & 1) * 16;
                const int grow = which * 192 + (2 * g + hh) * 32 + d0 + l15;
                const short8 wf = *(const short8*)(wqT + (size_t)grow * 192 + ks * 32 + lg * 8);
                if (which < 2) {
#pragma unroll
                    for (int nt = 0; nt < 4; ++nt) aq[ci][nt] = MFMA(wf, xf[nt], aq[ci][nt]);
                } else {                       // v: normal orientation
#pragma unroll
                    for (int nt = 0; nt < 4; ++nt) aq[ci][nt] = MFMA(xf[nt], wf, aq[ci][nt]);
                }
            }
        }
        // epilogue (no adds/scales: bias pre-init, q pre-scaled)
#pragma unroll
        for (int ci = 0; ci < 3; ++ci) {
            const int t = w + 4 * ci;
            const int which = t >> 2, sub = t & 3;
            const int hh = sub >> 1, d0 = (sub & 1) * 16;
            if (which < 2) {                   // lane: col=tok, rows = 4 qkv-cols
                const int rbase = hh * 32 + d0 + 4 * lg;
#pragma unroll
                for (int nt = 0; nt < 4; ++nt) {
                    const int tok = 16 * nt + l15;
                    uint2 pk;
                    pk.x = pack2(aq[ci][nt][0], aq[ci][nt][1]);
                    pk.y = pack2(aq[ci][nt][2], aq[ci][nt][3]);
                    if (which == 0) *(uint2*)(&qp_s[tok][rbase]) = pk;
                    else            *(uint2*)(&kp_s[tok][rbase]) = pk;
                }
            } else {                           // v: lane holds 4 consecutive toks at one d
                const int dcol = hh * 32 + d0 + l15;
#pragma unroll
                for (int nt = 0; nt < 4; ++nt) {
                    uint2 pk;
                    pk.x = pack2(aq[ci][nt][0], aq[ci][nt][1]);
                    pk.y = pack2(aq[ci][nt][2], aq[ci][nt][3]);
                    *(uint2*)(&vT_s[dcol][16 * nt + 4 * lg]) = pk;
                }
            }
        }
        __syncthreads();   // A: q/k/vT ready

        // ==== phase 2a: S = q k^T for this wave's 2 q-tiles of its head ====
        short8 qf[2], kf[4];
#pragma unroll
        for (int mq = 0; mq < 2; ++mq)
            qf[mq] = *(const short8*)(&qp_s[16 * (qt0 + mq) + l15][h_loc * 32 + lg * 8]);
#pragma unroll
        for (int nt = 0; nt < 4; ++nt)
            kf[nt] = *(const short8*)(&kp_s[16 * nt + l15][h_loc * 32 + lg * 8]);
        f32x4 s[2][4];
        const f32x4 z = {0.f, 0.f, 0.f, 0.f};
#pragma unroll
        for (int mq = 0; mq < 2; ++mq)
#pragma unroll
            for (int nt = 0; nt < 4; ++nt) s[mq][nt] = MFMA(qf[mq], kf[nt], z);
        __syncthreads();   // B: q/k dead -> reuse as p

        // ==== phase 2b: softmax: e = 2^(s*log2e + biasL); masked table -> 0 ====
        unsigned short (*p_buf)[72] = (h_loc == 0) ? qp_s : kp_s;
        const int h = 2 * g + h_loc;
#pragma unroll
        for (int mq = 0; mq < 2; ++mq) {
#pragma unroll
            for (int j = 0; j < 4; ++j) {
                const int q = 16 * (qt0 + mq) + 4 * lg + j;
                const u16x4 bb = *(const u16x4*)(bias_t + (((h * 64 + q) * 16 + l15) << 2));
                float e[4], sum = 0.f;
#pragma unroll
                for (int nt = 0; nt < 4; ++nt) {
                    e[nt] = __builtin_exp2f(fmaf(s[mq][nt][j], L2E, bf2f(bb[nt])));
                    sum += e[nt];
                }
                sum += __shfl_xor(sum, 1);
                sum += __shfl_xor(sum, 2);
                sum += __shfl_xor(sum, 4);
                sum += __shfl_xor(sum, 8);
                const float ri = __builtin_amdgcn_rcpf(sum);
#pragma unroll
                for (int nt = 0; nt < 4; ++nt)
                    p_buf[q][16 * nt + l15] = f2bf1(e[nt] * ri);
            }
        }

        // ==== phase 3: O^T = V^T P^T; write oh straight to global (bf16) ====
        f32x4 o[2][2];
#pragma unroll
        for (int dm = 0; dm < 2; ++dm)
#pragma unroll
            for (int qn = 0; qn < 2; ++qn) o[dm][qn] = z;
#pragma unroll
        for (int ks2 = 0; ks2 < 2; ++ks2) {
            short8 pf[2];
#pragma unroll
            for (int qn = 0; qn < 2; ++qn)
                pf[qn] = *(const short8*)(&p_buf[16 * (qt0 + qn) + l15][ks2 * 32 + lg * 8]);
#pragma unroll
            for (int dm = 0; dm < 2; ++dm) {
                const short8 vf = *(const short8*)(&vT_s[h_loc * 32 + 16 * dm + l15][ks2 * 32 + lg * 8]);
#pragma unroll
                for (int qn = 0; qn < 2; ++qn) o[dm][qn] = MFMA(vf, pf[qn], o[dm][qn]);
            }
        }
#pragma unroll
        for (int dm = 0; dm < 2; ++dm)
#pragma unroll
            for (int qn = 0; qn < 2; ++qn) {
                const int tok = 16 * (qt0 + qn) + l15;
                const int c0 = h * 32 + 16 * dm + 4 * lg;
                uint2 pk;
                pk.x = pack2(o[dm][qn][0], o[dm][qn][1]);
                pk.y = pack2(o[dm][qn][2], o[dm][qn][3]);
                *(uint2*)(oh_ws + (size_t)wing * 12288 + tok * 192 + c0) = pk;
            }
        if (g < 2) __syncthreads();   // D: protect qp/kp/vT reads vs next group's writes
    }
}

// ================= K2: GEMM2 (oh @ w_out + b_out) + rolled store =============
__global__ __launch_bounds__(256, 6)
void gemm2_out(const unsigned short* __restrict__ oh_ws,
               const unsigned short* __restrict__ woT,   // bf16 [192][192]
               const float* __restrict__ b_out,
               float* __restrict__ out) {
    __shared__ unsigned short oh_s[64][200];   // 25.6 KB -> 6 blocks/CU

    const int tid = threadIdx.x;
    const int w   = tid >> 6;
    const int l   = tid & 63;
    const int l15 = l & 15, lg = l >> 4;
    const int wing = blockIdx.x;
    const int b   = wing >> 10;
    const int win = wing & (NWIN - 1);
    const int wy  = win >> 5, wx = win & 31;

    // stage oh (fully coalesced uint4)
#pragma unroll
    for (int it = 0; it < 6; ++it) {
        const int i = tid + 256 * it;          // 0..1535
        const int t = i / 24, c8 = i % 24;
        const uint4 u = *(const uint4*)(oh_ws + (size_t)wing * 12288 + t * 192 + c8 * 8);
        *(uint4*)(&oh_s[t][c8 * 8]) = u;
    }
    __syncthreads();

#pragma unroll
    for (int ci = 0; ci < 3; ++ci) {
        const int oc0 = 16 * (w + 4 * ci);
        const float4 bo = *reinterpret_cast<const float4*>(b_out + oc0 + 4 * lg);
        f32x4 acc[4];
#pragma unroll
        for (int nt = 0; nt < 4; ++nt) acc[nt] = f32x4{bo.x, bo.y, bo.z, bo.w};
#pragma unroll
        for (int ks = 0; ks < 6; ++ks) {
            const short8 af = *(const short8*)(woT + (size_t)(oc0 + l15) * 192 + ks * 32 + lg * 8);
#pragma unroll
            for (int nt = 0; nt < 4; ++nt) {
                const short8 bfr = *(const short8*)(&oh_s[16 * nt + l15][ks * 32 + lg * 8]);
                acc[nt] = MFMA(af, bfr, acc[nt]);
            }
        }
#pragma unroll
        for (int nt = 0; nt < 4; ++nt) {
            const int tok = 16 * nt + l15;
            const int pr = ((wy << 3) + (tok >> 3) + 4) & (IMG - 1);
            const int pc = ((wx << 3) + (tok & 7) + 4) & (IMG - 1);
            float* orow = out + (size_t)((b * IMG + pr) * IMG + pc) * 192;
            *reinterpret_cast<float4*>(orow + oc0 + 4 * lg) =
                make_float4(acc[nt][0], acc[nt][1], acc[nt][2], acc[nt][3]);
        }
    }
}

extern "C" void kernel_launch(void* const* d_in, const int* in_sizes, int n_in,
                              void* d_out, int out_size, void* d_ws, size_t ws_size,
                              hipStream_t stream) {
    (void)in_sizes; (void)n_in; (void)out_size; (void)ws_size;
    const float* x       = (const float*)d_in[0];
    const float* w_qkv   = (const float*)d_in[1];
    const float* b_qkv   = (const float*)d_in[2];
    const float* rel_pos = (const float*)d_in[3];
    const float* w_out   = (const float*)d_in[4];
    const float* b_out   = (const float*)d_in[5];
    float* out = (float*)d_out;

    unsigned short* wqT   = (unsigned short*)d_ws;       // 110592 hw
    unsigned short* woT   = wqT + 576 * 192;             //  36864 hw
    unsigned short* bias2 = woT + 192 * 192;             //  2*24576 hw (plain + masked)
    float*          bq2   = (float*)(bias2 + 2 * 24576); //  576 f32
    unsigned short* oh_ws = (unsigned short*)(bq2 + 576);// 4096*64*192 hw = 100.7 MB

    to_bf16_T<<<dim3(9, 6), 256, 0, stream>>>(w_qkv, wqT, 192, 576, 192, SCALE);
    to_bf16_T<<<dim3(3, 6), 256, 0, stream>>>(w_out, woT, 192, 192, 0, 1.0f);
    build_bias<<<dim3(96), 256, 0, stream>>>(rel_pos, b_qkv, bias2, bq2);

    qkv_attn<<<dim3(4 * NWIN), dim3(256), 0, stream>>>(x, bq2, bias2, wqT, oh_ws);
    gemm2_out<<<dim3(4 * NWIN), dim3(256), 0, stream>>>(oh_ws, woT, b_out, out);
}

// Round 9
// 314.909 us; speedup vs baseline: 1.3775x; 1.0348x over previous
//
#include <hip/hip_runtime.h>
#include <hip/hip_bf16.h>

typedef __attribute__((ext_vector_type(8))) short short8;
typedef __attribute__((ext_vector_type(4))) float f32x4;
typedef __attribute__((ext_vector_type(4))) unsigned short u16x4;

#define MFMA(a, b, c) __builtin_amdgcn_mfma_f32_16x16x32_bf16((a), (b), (c), 0, 0, 0)

namespace {
constexpr int IMG = 256;
constexpr int NWIN = 1024;
constexpr float SCALE = 0.17677669529663687f;  // 32^-0.5
constexpr float L2E   = 1.4426950408889634f;   // log2(e)
}

__device__ __forceinline__ unsigned short f2bf1(float f) {
    __hip_bfloat16 h = __float2bfloat16(f);
    union { __hip_bfloat16 h; unsigned short u; } v; v.h = h;
    return v.u;
}
__device__ __forceinline__ unsigned pack2(float a, float b) {
    __hip_bfloat162 h = __float22bfloat162_rn(make_float2(a, b));
    union { __hip_bfloat162 h; unsigned u; } v; v.h = h;
    return v.u;
}
__device__ __forceinline__ float bf2f(unsigned short h) {
    union { unsigned u; float f; } v; v.u = ((unsigned)h) << 16;
    return v.f;
}

// fp32 [K][N] -> bf16 [N][K]; output rows (= original cols) < scale_n get *scale
__global__ __launch_bounds__(256) void to_bf16_T(const float* __restrict__ in,
                                                 unsigned short* __restrict__ out,
                                                 int K, int N, int scale_n, float scale) {
    __shared__ float tile[32][65];
    const int t = threadIdx.x;
    const int nb = blockIdx.x * 64, kb = blockIdx.y * 32;
    const int tn = t & 63, tk = t >> 6;
#pragma unroll
    for (int p = 0; p < 8; ++p)
        tile[p * 4 + tk][tn] = in[(size_t)(kb + p * 4 + tk) * N + nb + tn];
    __syncthreads();
    const int n = t >> 2, kc = (t & 3) * 8;
    const float s = (nb + n) < scale_n ? scale : 1.0f;
    uint4 u;
    u.x = pack2(tile[kc + 0][n] * s, tile[kc + 1][n] * s);
    u.y = pack2(tile[kc + 2][n] * s, tile[kc + 3][n] * s);
    u.z = pack2(tile[kc + 4][n] * s, tile[kc + 5][n] * s);
    u.w = pack2(tile[kc + 6][n] * s, tile[kc + 7][n] * s);
    *(uint4*)(out + (size_t)(nb + n) * K + kb + kc) = u;
}

// bias3[(h*64+q)*64 + k] (and +24576 masked variant), pre-multiplied by log2e.
// k-contiguous so the swapped softmax loads u16x4 over k. Also bq2[576].
__global__ __launch_bounds__(256) void build_bias(const float* __restrict__ rel_pos,
                                                  const float* __restrict__ b_qkv,
                                                  unsigned short* __restrict__ bias3,
                                                  float* __restrict__ bq2) {
    const int o = blockIdx.x * 256 + threadIdx.x;   // 0..24575
    const int k = o & 63, q = (o >> 6) & 63, h = o >> 12;
    const int qy = q >> 3, qx = q & 7, ky = k >> 3, kx = k & 7;
    const float bv = rel_pos[h * 225 + (qy - ky + 7) * 15 + (qx - kx + 7)] * L2E;
    bias3[o] = f2bf1(bv);
    const bool masked = (q < 4) != (k < 4);
    bias3[24576 + o] = masked ? f2bf1(-30000.0f) : f2bf1(bv);
    if (blockIdx.x == 0) {
        for (int i = threadIdx.x; i < 576; i += 256)
            bq2[i] = b_qkv[i] * (i < 192 ? SCALE : 1.0f);
    }
}

// ================= K1: GEMM1 (bias C-init) + attention -> oh_ws (bf16) =======
__global__ __launch_bounds__(256, 3)
void qkv_attn(const float* __restrict__ x,
              const float* __restrict__ bq2,
              const unsigned short* __restrict__ bias3,  // [2][24576], *log2e
              const unsigned short* __restrict__ wqT,    // bf16 [576][192], q-rows pre-scaled
              unsigned short* __restrict__ oh_ws) {      // [4096][64][192]
    __shared__ unsigned short x_s[64][200];   // 25.6 KB
    __shared__ unsigned short qp_s[64][72];   //  9.2 KB  (q / P-head0, aliased)
    __shared__ unsigned short kp_s[64][72];   //  9.2 KB  (k / P-head1, aliased)
    __shared__ unsigned short vT_s[64][72];   //  9.2 KB  -> 53248 B, 3 blocks/CU

    const int tid = threadIdx.x;
    const int w   = tid >> 6;
    const int l   = tid & 63;
    const int l15 = l & 15, lg = l >> 4;
    const int wing = blockIdx.x;
    const int b   = wing >> 10;
    const int win = wing & (NWIN - 1);
    const int wy  = win >> 5, wx = win & 31;
    const unsigned short* bias_t = bias3 + ((win == NWIN - 1) ? 24576 : 0);

    // stage x window -> bf16 LDS (roll(-4,-4) folded; strength-reduced t,r)
    {
        int t = tid / 48, r = tid % 48;
#pragma unroll
        for (int it = 0; it < 12; ++it) {
            const int pr = ((wy << 3) + (t >> 3) + 4) & (IMG - 1);
            const int pc = ((wx << 3) + (t & 7) + 4) & (IMG - 1);
            const float4 xv = *reinterpret_cast<const float4*>(
                x + ((size_t)((b * IMG + pr) * IMG + pc)) * 192 + r * 4);
            uint2 pk; pk.x = pack2(xv.x, xv.y); pk.y = pack2(xv.z, xv.w);
            *(uint2*)(&x_s[t][r * 4]) = pk;
            r += 16; t += 5;
            if (r >= 48) { r -= 48; t += 1; }
        }
    }
    __syncthreads();

    const int h_loc = w >> 1;
    const int qt0   = 2 * (w & 1);

#pragma unroll 1
    for (int g = 0; g < 3; ++g) {             // heads 2g, 2g+1
        // ==== phase 1: GEMM1; wave owns col-tiles {w, w+4, w+8}; bias via C-init
        f32x4 aq[3][4];
#pragma unroll
        for (int ci = 0; ci < 3; ++ci) {
            const int t = w + 4 * ci;
            const int which = t >> 2, sub = t & 3;
            const int hh = sub >> 1, d0 = (sub & 1) * 16;
            f32x4 c0;
            if (which < 2) {                   // transposed D[col][tok]: bias per row
                const float4 b4 = *reinterpret_cast<const float4*>(
                    bq2 + which * 192 + (2 * g + hh) * 32 + d0 + 4 * lg);
                c0 = f32x4{b4.x, b4.y, b4.z, b4.w};
            } else {                           // normal D[tok][vcol]: bias per col
                const float bb = bq2[384 + (2 * g + hh) * 32 + d0 + l15];
                c0 = f32x4{bb, bb, bb, bb};
            }
#pragma unroll
            for (int nt = 0; nt < 4; ++nt) aq[ci][nt] = c0;
        }

        __builtin_amdgcn_s_setprio(1);
#pragma unroll
        for (int ks = 0; ks < 6; ++ks) {
            short8 xf[4];
#pragma unroll
            for (int nt = 0; nt < 4; ++nt)
                xf[nt] = *(const short8*)(&x_s[16 * nt + l15][ks * 32 + lg * 8]);
#pragma unroll
            for (int ci = 0; ci < 3; ++ci) {
                const int t = w + 4 * ci;
                const int which = t >> 2, sub = t & 3;
                const int hh = sub >> 1, d0 = (sub & 1) * 16;
                const int grow = which * 192 + (2 * g + hh) * 32 + d0 + l15;
                const short8 wf = *(const short8*)(wqT + (size_t)grow * 192 + ks * 32 + lg * 8);
                if (which < 2) {
#pragma unroll
                    for (int nt = 0; nt < 4; ++nt) aq[ci][nt] = MFMA(wf, xf[nt], aq[ci][nt]);
                } else {                       // v: normal orientation
#pragma unroll
                    for (int nt = 0; nt < 4; ++nt) aq[ci][nt] = MFMA(xf[nt], wf, aq[ci][nt]);
                }
            }
        }
        __builtin_amdgcn_s_setprio(0);

        // epilogue (no adds/scales: bias pre-init, q pre-scaled)
#pragma unroll
        for (int ci = 0; ci < 3; ++ci) {
            const int t = w + 4 * ci;
            const int which = t >> 2, sub = t & 3;
            const int hh = sub >> 1, d0 = (sub & 1) * 16;
            if (which < 2) {                   // lane: col=tok, rows = 4 qkv-cols
                const int rbase = hh * 32 + d0 + 4 * lg;
#pragma unroll
                for (int nt = 0; nt < 4; ++nt) {
                    const int tok = 16 * nt + l15;
                    uint2 pk;
                    pk.x = pack2(aq[ci][nt][0], aq[ci][nt][1]);
                    pk.y = pack2(aq[ci][nt][2], aq[ci][nt][3]);
                    if (which == 0) *(uint2*)(&qp_s[tok][rbase]) = pk;
                    else            *(uint2*)(&kp_s[tok][rbase]) = pk;
                }
            } else {                           // v: lane holds 4 consecutive toks at one d
                const int dcol = hh * 32 + d0 + l15;
#pragma unroll
                for (int nt = 0; nt < 4; ++nt) {
                    uint2 pk;
                    pk.x = pack2(aq[ci][nt][0], aq[ci][nt][1]);
                    pk.y = pack2(aq[ci][nt][2], aq[ci][nt][3]);
                    *(uint2*)(&vT_s[dcol][16 * nt + 4 * lg]) = pk;
                }
            }
        }
        __syncthreads();   // A: q/k/vT ready

        // ==== phase 2a: S^T = MFMA(kf, qf): rows=k-tokens, cols=q-tokens ====
        short8 qf[2], kf[4];
#pragma unroll
        for (int mq = 0; mq < 2; ++mq)
            qf[mq] = *(const short8*)(&qp_s[16 * (qt0 + mq) + l15][h_loc * 32 + lg * 8]);
#pragma unroll
        for (int nt = 0; nt < 4; ++nt)
            kf[nt] = *(const short8*)(&kp_s[16 * nt + l15][h_loc * 32 + lg * 8]);
        f32x4 s[2][4];
        const f32x4 z = {0.f, 0.f, 0.f, 0.f};
#pragma unroll
        for (int mq = 0; mq < 2; ++mq)
#pragma unroll
            for (int nt = 0; nt < 4; ++nt) s[mq][nt] = MFMA(kf[nt], qf[mq], z);
        __syncthreads();   // B: q/k dead -> reuse as P

        // ==== phase 2b: swapped softmax. lane: q = 16(qt0+mq)+l15 fixed,
        //      k = 16nt+4lg+j. Reduce over lanes' lg bits: xor 16, 32 only. ====
        unsigned short (*p_buf)[72] = (h_loc == 0) ? qp_s : kp_s;
        const int h = 2 * g + h_loc;
        float ri[2];
#pragma unroll
        for (int mq = 0; mq < 2; ++mq) {
            const int q = 16 * (qt0 + mq) + l15;
            float e[4][4], sum = 0.f;
#pragma unroll
            for (int nt = 0; nt < 4; ++nt) {
                const u16x4 bb = *(const u16x4*)(bias_t + (h * 64 + q) * 64 + 16 * nt + 4 * lg);
                float psum = 0.f;
#pragma unroll
                for (int j = 0; j < 4; ++j) {
                    e[nt][j] = __builtin_exp2f(fmaf(s[mq][nt][j], L2E, bf2f(bb[j])));
                    psum += e[nt][j];
                }
                sum += psum;
            }
            sum += __shfl_xor(sum, 16);
            sum += __shfl_xor(sum, 32);
            ri[mq] = __builtin_amdgcn_rcpf(sum);
            // store raw e (normalization folded into PV epilogue)
#pragma unroll
            for (int nt = 0; nt < 4; ++nt) {
                uint2 pk;
                pk.x = pack2(e[nt][0], e[nt][1]);
                pk.y = pack2(e[nt][2], e[nt][3]);
                *(uint2*)(&p_buf[q][16 * nt + 4 * lg]) = pk;
            }
        }

        // ==== phase 3: O^T = V^T P^T; scale by ri; write oh to global ====
        f32x4 o[2][2];
#pragma unroll
        for (int dm = 0; dm < 2; ++dm)
#pragma unroll
            for (int qn = 0; qn < 2; ++qn) o[dm][qn] = z;
#pragma unroll
        for (int ks2 = 0; ks2 < 2; ++ks2) {
            short8 pf[2];
#pragma unroll
            for (int qn = 0; qn < 2; ++qn)
                pf[qn] = *(const short8*)(&p_buf[16 * (qt0 + qn) + l15][ks2 * 32 + lg * 8]);
#pragma unroll
            for (int dm = 0; dm < 2; ++dm) {
                const short8 vf = *(const short8*)(&vT_s[h_loc * 32 + 16 * dm + l15][ks2 * 32 + lg * 8]);
#pragma unroll
                for (int qn = 0; qn < 2; ++qn) o[dm][qn] = MFMA(vf, pf[qn], o[dm][qn]);
            }
        }
#pragma unroll
        for (int dm = 0; dm < 2; ++dm)
#pragma unroll
            for (int qn = 0; qn < 2; ++qn) {
                const int tok = 16 * (qt0 + qn) + l15;
                const int c0 = h * 32 + 16 * dm + 4 * lg;
                const float rr = ri[qn];
                uint2 pk;
                pk.x = pack2(o[dm][qn][0] * rr, o[dm][qn][1] * rr);
                pk.y = pack2(o[dm][qn][2] * rr, o[dm][qn][3] * rr);
                *(uint2*)(oh_ws + (size_t)wing * 12288 + tok * 192 + c0) = pk;
            }
        if (g < 2) __syncthreads();   // D: protect qp/kp/vT reads vs next group's writes
    }
}

// ================= K2: GEMM2 (oh @ w_out + b_out) + rolled store =============
__global__ __launch_bounds__(256, 6)
void gemm2_out(const unsigned short* __restrict__ oh_ws,
               const unsigned short* __restrict__ woT,   // bf16 [192][192]
               const float* __restrict__ b_out,
               float* __restrict__ out) {
    __shared__ unsigned short oh_s[64][200];   // 25.6 KB -> 6 blocks/CU

    const int tid = threadIdx.x;
    const int w   = tid >> 6;
    const int l   = tid & 63;
    const int l15 = l & 15, lg = l >> 4;
    const int wing = blockIdx.x;
    const int b   = wing >> 10;
    const int win = wing & (NWIN - 1);
    const int wy  = win >> 5, wx = win & 31;

    // stage oh (fully coalesced uint4)
#pragma unroll
    for (int it = 0; it < 6; ++it) {
        const int i = tid + 256 * it;          // 0..1535
        const int t = i / 24, c8 = i % 24;
        const uint4 u = *(const uint4*)(oh_ws + (size_t)wing * 12288 + t * 192 + c8 * 8);
        *(uint4*)(&oh_s[t][c8 * 8]) = u;
    }
    __syncthreads();

#pragma unroll
    for (int ci = 0; ci < 3; ++ci) {
        const int oc0 = 16 * (w + 4 * ci);
        const float4 bo = *reinterpret_cast<const float4*>(b_out + oc0 + 4 * lg);
        f32x4 acc[4];
#pragma unroll
        for (int nt = 0; nt < 4; ++nt) acc[nt] = f32x4{bo.x, bo.y, bo.z, bo.w};
#pragma unroll
        for (int ks = 0; ks < 6; ++ks) {
            const short8 af = *(const short8*)(woT + (size_t)(oc0 + l15) * 192 + ks * 32 + lg * 8);
#pragma unroll
            for (int nt = 0; nt < 4; ++nt) {
                const short8 bfr = *(const short8*)(&oh_s[16 * nt + l15][ks * 32 + lg * 8]);
                acc[nt] = MFMA(af, bfr, acc[nt]);
            }
        }
#pragma unroll
        for (int nt = 0; nt < 4; ++nt) {
            const int tok = 16 * nt + l15;
            const int pr = ((wy << 3) + (tok >> 3) + 4) & (IMG - 1);
            const int pc = ((wx << 3) + (tok & 7) + 4) & (IMG - 1);
            float* orow = out + (size_t)((b * IMG + pr) * IMG + pc) * 192;
            *reinterpret_cast<float4*>(orow + oc0 + 4 * lg) =
                make_float4(acc[nt][0], acc[nt][1], acc[nt][2], acc[nt][3]);
        }
    }
}

extern "C" void kernel_launch(void* const* d_in, const int* in_sizes, int n_in,
                              void* d_out, int out_size, void* d_ws, size_t ws_size,
                              hipStream_t stream) {
    (void)in_sizes; (void)n_in; (void)out_size; (void)ws_size;
    const float* x       = (const float*)d_in[0];
    const float* w_qkv   = (const float*)d_in[1];
    const float* b_qkv   = (const float*)d_in[2];
    const float* rel_pos = (const float*)d_in[3];
    const float* w_out   = (const float*)d_in[4];
    const float* b_out   = (const float*)d_in[5];
    float* out = (float*)d_out;

    unsigned short* wqT   = (unsigned short*)d_ws;       // 110592 hw
    unsigned short* woT   = wqT + 576 * 192;             //  36864 hw
    unsigned short* bias3 = woT + 192 * 192;             //  2*24576 hw (plain + masked)
    float*          bq2   = (float*)(bias3 + 2 * 24576); //  576 f32
    unsigned short* oh_ws = (unsigned short*)(bq2 + 576);// 4096*64*192 hw = 100.7 MB

    to_bf16_T<<<dim3(9, 6), 256, 0, stream>>>(w_qkv, wqT, 192, 576, 192, SCALE);
    to_bf16_T<<<dim3(3, 6), 256, 0, stream>>>(w_out, woT, 192, 192, 0, 1.0f);
    build_bias<<<dim3(96), 256, 0, stream>>>(rel_pos, b_qkv, bias3, bq2);

    qkv_attn<<<dim3(4 * NWIN), dim3(256), 0, stream>>>(x, bq2, bias3, wqT, oh_ws);
    gemm2_out<<<dim3(4 * NWIN), dim3(256), 0, stream>>>(oh_ws, woT, b_out, out);
}

// Round 10
// 314.696 us; speedup vs baseline: 1.3785x; 1.0007x over previous
//
#include <hip/hip_runtime.h>
#include <hip/hip_bf16.h>

typedef __attribute__((ext_vector_type(8))) short short8;
typedef __attribute__((ext_vector_type(4))) float f32x4;

#define MFMA(a, b, c) __builtin_amdgcn_mfma_f32_16x16x32_bf16((a), (b), (c), 0, 0, 0)

namespace {
constexpr int IMG = 256;
constexpr int NWIN = 1024;
constexpr float SCALE = 0.17677669529663687f;  // 32^-0.5
constexpr float L2E   = 1.4426950408889634f;   // log2(e)
}

__device__ __forceinline__ unsigned pack2(float a, float b) {
    __hip_bfloat162 h = __float22bfloat162_rn(make_float2(a, b));
    union { __hip_bfloat162 h; unsigned u; } v; v.h = h;
    return v.u;
}

// fp32 [K][N] -> bf16 [N][K]; output rows (= original cols) < scale_n get *scale
__global__ __launch_bounds__(256) void to_bf16_T(const float* __restrict__ in,
                                                 unsigned short* __restrict__ out,
                                                 int K, int N, int scale_n, float scale) {
    __shared__ float tile[32][65];
    const int t = threadIdx.x;
    const int nb = blockIdx.x * 64, kb = blockIdx.y * 32;
    const int tn = t & 63, tk = t >> 6;
#pragma unroll
    for (int p = 0; p < 8; ++p)
        tile[p * 4 + tk][tn] = in[(size_t)(kb + p * 4 + tk) * N + nb + tn];
    __syncthreads();
    const int n = t >> 2, kc = (t & 3) * 8;
    const float s = (nb + n) < scale_n ? scale : 1.0f;
    uint4 u;
    u.x = pack2(tile[kc + 0][n] * s, tile[kc + 1][n] * s);
    u.y = pack2(tile[kc + 2][n] * s, tile[kc + 3][n] * s);
    u.z = pack2(tile[kc + 4][n] * s, tile[kc + 5][n] * s);
    u.w = pack2(tile[kc + 6][n] * s, tile[kc + 7][n] * s);
    *(uint4*)(out + (size_t)(nb + n) * K + kb + kc) = u;
}

// f32 bias tables (pre-multiplied by log2e): biasf[(h*64+q)*64+k], +24576 masked.
// Also bq2[576] (q-part * SCALE).
__global__ __launch_bounds__(256) void build_bias(const float* __restrict__ rel_pos,
                                                  const float* __restrict__ b_qkv,
                                                  float* __restrict__ biasf,
                                                  float* __restrict__ bq2) {
    const int o = blockIdx.x * 256 + threadIdx.x;   // 0..24575
    const int k = o & 63, q = (o >> 6) & 63, h = o >> 12;
    const int qy = q >> 3, qx = q & 7, ky = k >> 3, kx = k & 7;
    const float bv = rel_pos[h * 225 + (qy - ky + 7) * 15 + (qx - kx + 7)] * L2E;
    biasf[o] = bv;
    const bool masked = (q < 4) != (k < 4);
    biasf[24576 + o] = masked ? -30000.0f : bv;
    if (blockIdx.x == 0) {
        for (int i = threadIdx.x; i < 576; i += 256)
            bq2[i] = b_qkv[i] * (i < 192 ? SCALE : 1.0f);
    }
}

// ================= K1: GEMM1 (bias C-init) + attention -> oh_ws (bf16) =======
__global__ __launch_bounds__(256, 3)
void qkv_attn(const float* __restrict__ x,
              const float* __restrict__ bq2,
              const float* __restrict__ biasf,          // [2][24576] f32, *log2e
              const unsigned short* __restrict__ wqT,   // bf16 [576][192], q-rows pre-scaled
              unsigned short* __restrict__ oh_ws) {     // [4096][64][192]
    __shared__ unsigned short x_s[64][200];   // 25.6 KB
    __shared__ unsigned short qp_s[64][72];   //  9.2 KB  (q / P-head0, aliased)
    __shared__ unsigned short kp_s[64][72];   //  9.2 KB  (k / P-head1, aliased)
    __shared__ unsigned short vT_s[64][72];   //  9.2 KB  -> 53248 B, 3 blocks/CU

    const int tid = threadIdx.x;
    const int w   = tid >> 6;
    const int l   = tid & 63;
    const int l15 = l & 15, lg = l >> 4;
    const int wing = blockIdx.x;
    const int b   = wing >> 10;
    const int win = wing & (NWIN - 1);
    const int wy  = win >> 5, wx = win & 31;
    const float* bias_t = biasf + ((win == NWIN - 1) ? 24576 : 0);

    // ---- stage x window: thread = (row, chunk); no div/mod, coalesced ----
    {
        const int t  = tid >> 2;               // token 0..63
        const int c0 = tid & 3;
        const int pr = ((wy << 3) + (t >> 3) + 4) & (IMG - 1);
        const int pc = ((wx << 3) + (t & 7) + 4) & (IMG - 1);
        const float* xrow = x + ((size_t)((b * IMG + pr) * IMG + pc)) * 192;
#pragma unroll
        for (int i = 0; i < 12; ++i) {
            const int c = c0 + 4 * i;          // 0..47
            const float4 xv = *reinterpret_cast<const float4*>(xrow + c * 4);
            uint2 pk; pk.x = pack2(xv.x, xv.y); pk.y = pack2(xv.z, xv.w);
            *(uint2*)(&x_s[t][c * 4]) = pk;
        }
    }
    __syncthreads();

    const int h_loc = w >> 1;
    const int qt0   = 2 * (w & 1);

#pragma unroll 1
    for (int g = 0; g < 3; ++g) {             // heads 2g, 2g+1
        // ==== phase 1: GEMM1; wave owns col-tiles {w, w+4, w+8}; bias via C-init
        f32x4 aq[3][4];
        const unsigned short* wp[3];
#pragma unroll
        for (int ci = 0; ci < 3; ++ci) {
            const int t = w + 4 * ci;
            const int which = t >> 2, sub = t & 3;
            const int hh = sub >> 1, d0 = (sub & 1) * 16;
            const int grow = which * 192 + (2 * g + hh) * 32 + d0 + l15;
            wp[ci] = wqT + (size_t)grow * 192 + lg * 8;
            f32x4 c0;
            if (which < 2) {                   // transposed D[col][tok]: bias per row
                const float4 b4 = *reinterpret_cast<const float4*>(
                    bq2 + which * 192 + (2 * g + hh) * 32 + d0 + 4 * lg);
                c0 = f32x4{b4.x, b4.y, b4.z, b4.w};
            } else {                           // normal D[tok][vcol]: bias per col
                const float bb = bq2[384 + (2 * g + hh) * 32 + d0 + l15];
                c0 = f32x4{bb, bb, bb, bb};
            }
#pragma unroll
            for (int nt = 0; nt < 4; ++nt) aq[ci][nt] = c0;
        }

        __builtin_amdgcn_s_setprio(1);
#pragma unroll
        for (int ks = 0; ks < 6; ++ks) {
            short8 xf[4];
#pragma unroll
            for (int nt = 0; nt < 4; ++nt)
                xf[nt] = *(const short8*)(&x_s[16 * nt + l15][ks * 32 + lg * 8]);
#pragma unroll
            for (int ci = 0; ci < 3; ++ci) {
                const short8 wf = *(const short8*)wp[ci];
                wp[ci] += 32;
                if (ci < 2 ? ((w + 4 * ci) >> 2) < 2 : ((w + 8) >> 2) < 2) {
                    // q/k tiles: transposed orientation
#pragma unroll
                    for (int nt = 0; nt < 4; ++nt) aq[ci][nt] = MFMA(wf, xf[nt], aq[ci][nt]);
                } else {
                    // v tiles: normal orientation
#pragma unroll
                    for (int nt = 0; nt < 4; ++nt) aq[ci][nt] = MFMA(xf[nt], wf, aq[ci][nt]);
                }
            }
        }
        __builtin_amdgcn_s_setprio(0);

        // epilogue (no adds/scales: bias pre-init, q pre-scaled)
#pragma unroll
        for (int ci = 0; ci < 3; ++ci) {
            const int t = w + 4 * ci;
            const int which = t >> 2, sub = t & 3;
            const int hh = sub >> 1, d0 = (sub & 1) * 16;
            if (which < 2) {                   // lane: col=tok, rows = 4 qkv-cols
                const int rbase = hh * 32 + d0 + 4 * lg;
#pragma unroll
                for (int nt = 0; nt < 4; ++nt) {
                    const int tok = 16 * nt + l15;
                    uint2 pk;
                    pk.x = pack2(aq[ci][nt][0], aq[ci][nt][1]);
                    pk.y = pack2(aq[ci][nt][2], aq[ci][nt][3]);
                    if (which == 0) *(uint2*)(&qp_s[tok][rbase]) = pk;
                    else            *(uint2*)(&kp_s[tok][rbase]) = pk;
                }
            } else {                           // v: lane holds 4 consecutive toks at one d
                const int dcol = hh * 32 + d0 + l15;
#pragma unroll
                for (int nt = 0; nt < 4; ++nt) {
                    uint2 pk;
                    pk.x = pack2(aq[ci][nt][0], aq[ci][nt][1]);
                    pk.y = pack2(aq[ci][nt][2], aq[ci][nt][3]);
                    *(uint2*)(&vT_s[dcol][16 * nt + 4 * lg]) = pk;
                }
            }
        }
        __syncthreads();   // A: q/k/vT ready (no global stores outstanding here)

        // ==== phase 2a: S^T = MFMA(kf, qf): rows=k-tokens, cols=q-tokens ====
        short8 qf[2], kf[4];
#pragma unroll
        for (int mq = 0; mq < 2; ++mq)
            qf[mq] = *(const short8*)(&qp_s[16 * (qt0 + mq) + l15][h_loc * 32 + lg * 8]);
#pragma unroll
        for (int nt = 0; nt < 4; ++nt)
            kf[nt] = *(const short8*)(&kp_s[16 * nt + l15][h_loc * 32 + lg * 8]);
        f32x4 s[2][4];
        const f32x4 z = {0.f, 0.f, 0.f, 0.f};
        __builtin_amdgcn_s_setprio(1);
#pragma unroll
        for (int mq = 0; mq < 2; ++mq)
#pragma unroll
            for (int nt = 0; nt < 4; ++nt) s[mq][nt] = MFMA(kf[nt], qf[mq], z);
        __builtin_amdgcn_s_setprio(0);
        __syncthreads();   // B: q/k dead -> reuse as P

        // ==== phase 2b: swapped softmax. lane: q = 16(qt0+mq)+l15 fixed,
        //      k = 16nt+4lg+j. Reduce over lg bits: xor 16, 32 only. ====
        unsigned short (*p_buf)[72] = (h_loc == 0) ? qp_s : kp_s;
        const int h = 2 * g + h_loc;
        float ri[2];
#pragma unroll
        for (int mq = 0; mq < 2; ++mq) {
            const int q = 16 * (qt0 + mq) + l15;
            const float* bq = bias_t + ((h * 64 + q) << 6) + 4 * lg;
            float e[4][4], sum = 0.f;
#pragma unroll
            for (int nt = 0; nt < 4; ++nt) {
                const float4 bb = *(const float4*)(bq + 16 * nt);
                e[nt][0] = __builtin_exp2f(fmaf(s[mq][nt][0], L2E, bb.x));
                e[nt][1] = __builtin_exp2f(fmaf(s[mq][nt][1], L2E, bb.y));
                e[nt][2] = __builtin_exp2f(fmaf(s[mq][nt][2], L2E, bb.z));
                e[nt][3] = __builtin_exp2f(fmaf(s[mq][nt][3], L2E, bb.w));
                sum += (e[nt][0] + e[nt][1]) + (e[nt][2] + e[nt][3]);
            }
            sum += __shfl_xor(sum, 16);
            sum += __shfl_xor(sum, 32);
            ri[mq] = __builtin_amdgcn_rcpf(sum);
            // store raw e (normalization folded into PV epilogue)
#pragma unroll
            for (int nt = 0; nt < 4; ++nt) {
                uint2 pk;
                pk.x = pack2(e[nt][0], e[nt][1]);
                pk.y = pack2(e[nt][2], e[nt][3]);
                *(uint2*)(&p_buf[q][16 * nt + 4 * lg]) = pk;
            }
        }

        // ==== phase 3: O^T = V^T P^T ====
        f32x4 o[2][2];
#pragma unroll
        for (int dm = 0; dm < 2; ++dm)
#pragma unroll
            for (int qn = 0; qn < 2; ++qn) o[dm][qn] = z;
        __builtin_amdgcn_s_setprio(1);
#pragma unroll
        for (int ks2 = 0; ks2 < 2; ++ks2) {
            short8 pf[2];
#pragma unroll
            for (int qn = 0; qn < 2; ++qn)
                pf[qn] = *(const short8*)(&p_buf[16 * (qt0 + qn) + l15][ks2 * 32 + lg * 8]);
#pragma unroll
            for (int dm = 0; dm < 2; ++dm) {
                const short8 vf = *(const short8*)(&vT_s[h_loc * 32 + 16 * dm + l15][ks2 * 32 + lg * 8]);
#pragma unroll
                for (int qn = 0; qn < 2; ++qn) o[dm][qn] = MFMA(vf, pf[qn], o[dm][qn]);
            }
        }
        __builtin_amdgcn_s_setprio(0);

        // Barrier BEFORE the oh stores: only LDS reads need draining here, so the
        // compiler's vmcnt(0) is cheap (no outstanding stores). The stores then
        // overlap the next group's phase 1.
        if (g < 2) __syncthreads();   // D: protect qp/kp/vT reads vs next group's writes

        // pack + store oh (fire-and-forget; drained naturally before barrier A
        // of the NEXT group, ~2K cycles later, or at kernel end for g==2)
#pragma unroll
        for (int dm = 0; dm < 2; ++dm)
#pragma unroll
            for (int qn = 0; qn < 2; ++qn) {
                const int tok = 16 * (qt0 + qn) + l15;
                const int c0 = h * 32 + 16 * dm + 4 * lg;
                const float rr = ri[qn];
                uint2 pk;
                pk.x = pack2(o[dm][qn][0] * rr, o[dm][qn][1] * rr);
                pk.y = pack2(o[dm][qn][2] * rr, o[dm][qn][3] * rr);
                *(uint2*)(oh_ws + (size_t)wing * 12288 + tok * 192 + c0) = pk;
            }
    }
}

// ================= K2: GEMM2 (oh @ w_out + b_out) + rolled store =============
__global__ __launch_bounds__(256, 6)
void gemm2_out(const unsigned short* __restrict__ oh_ws,
               const unsigned short* __restrict__ woT,   // bf16 [192][192]
               const float* __restrict__ b_out,
               float* __restrict__ out) {
    __shared__ unsigned short oh_s[64][200];   // 25.6 KB -> 6 blocks/CU

    const int tid = threadIdx.x;
    const int w   = tid >> 6;
    const int l   = tid & 63;
    const int l15 = l & 15, lg = l >> 4;
    const int wing = blockIdx.x;
    const int b   = wing >> 10;
    const int win = wing & (NWIN - 1);
    const int wy  = win >> 5, wx = win & 31;

    // stage oh (fully coalesced uint4)
#pragma unroll
    for (int it = 0; it < 6; ++it) {
        const int i = tid + 256 * it;          // 0..1535
        const int t = i / 24, c8 = i % 24;
        const uint4 u = *(const uint4*)(oh_ws + (size_t)wing * 12288 + t * 192 + c8 * 8);
        *(uint4*)(&oh_s[t][c8 * 8]) = u;
    }
    __syncthreads();

#pragma unroll
    for (int ci = 0; ci < 3; ++ci) {
        const int oc0 = 16 * (w + 4 * ci);
        const float4 bo = *reinterpret_cast<const float4*>(b_out + oc0 + 4 * lg);
        f32x4 acc[4];
#pragma unroll
        for (int nt = 0; nt < 4; ++nt) acc[nt] = f32x4{bo.x, bo.y, bo.z, bo.w};
#pragma unroll
        for (int ks = 0; ks < 6; ++ks) {
            const short8 af = *(const short8*)(woT + (size_t)(oc0 + l15) * 192 + ks * 32 + lg * 8);
#pragma unroll
            for (int nt = 0; nt < 4; ++nt) {
                const short8 bfr = *(const short8*)(&oh_s[16 * nt + l15][ks * 32 + lg * 8]);
                acc[nt] = MFMA(af, bfr, acc[nt]);
            }
        }
#pragma unroll
        for (int nt = 0; nt < 4; ++nt) {
            const int tok = 16 * nt + l15;
            const int pr = ((wy << 3) + (tok >> 3) + 4) & (IMG - 1);
            const int pc = ((wx << 3) + (tok & 7) + 4) & (IMG - 1);
            float* orow = out + (size_t)((b * IMG + pr) * IMG + pc) * 192;
            *reinterpret_cast<float4*>(orow + oc0 + 4 * lg) =
                make_float4(acc[nt][0], acc[nt][1], acc[nt][2], acc[nt][3]);
        }
    }
}

extern "C" void kernel_launch(void* const* d_in, const int* in_sizes, int n_in,
                              void* d_out, int out_size, void* d_ws, size_t ws_size,
                              hipStream_t stream) {
    (void)in_sizes; (void)n_in; (void)out_size; (void)ws_size;
    const float* x       = (const float*)d_in[0];
    const float* w_qkv   = (const float*)d_in[1];
    const float* b_qkv   = (const float*)d_in[2];
    const float* rel_pos = (const float*)d_in[3];
    const float* w_out   = (const float*)d_in[4];
    const float* b_out   = (const float*)d_in[5];
    float* out = (float*)d_out;

    unsigned short* wqT   = (unsigned short*)d_ws;       // 110592 hw
    unsigned short* woT   = wqT + 576 * 192;             //  36864 hw
    float*          biasf = (float*)(woT + 192 * 192);   //  2*24576 f32
    float*          bq2   = biasf + 2 * 24576;           //  576 f32
    unsigned short* oh_ws = (unsigned short*)(bq2 + 576);// 4096*64*192 hw = 100.7 MB

    to_bf16_T<<<dim3(9, 6), 256, 0, stream>>>(w_qkv, wqT, 192, 576, 192, SCALE);
    to_bf16_T<<<dim3(3, 6), 256, 0, stream>>>(w_out, woT, 192, 192, 0, 1.0f);
    build_bias<<<dim3(96), 256, 0, stream>>>(rel_pos, b_qkv, biasf, bq2);

    qkv_attn<<<dim3(4 * NWIN), dim3(256), 0, stream>>>(x, bq2, biasf, wqT, oh_ws);
    gemm2_out<<<dim3(4 * NWIN), dim3(256), 0, stream>>>(oh_ws, woT, b_out, out);
}